// Round 10
// baseline (466.023 us; speedup 1.0000x reference)
//
#include <hip/hip_runtime.h>
#include <cstddef>

// ---------------------------------------------------------------------------
// GNN forward: embed+posenc -> 2x TransformerConv(8 heads x 32) -> 2x GCNConv
// N=50000, E=400000, IN=63, D=32, HC=256.
// R10: attn K-dot via v_dot2_f32_bf16 (packed Q, 2 inst), exp2 builtin;
// kvqs 16 rows/block (halved weight L2 re-fetch); GCN gathers wave-per-node
// with even/odd lane-half edge split (serial depth halved, 8 loads in flight).
// No-max softmax; CSR built once; no per-edge atomics anywhere.
// ---------------------------------------------------------------------------

#define NH 8
#define HCH 256
#define D32 32
#define INCH 63
#define CSCALE 0.25503485356f   // log2(e) / sqrt(32)

__device__ __forceinline__ unsigned short f2bf(float f) {
    unsigned u = __float_as_uint(f);
    u += 0x7fff + ((u >> 16) & 1);   // RNE
    return (unsigned short)(u >> 16);
}
__device__ __forceinline__ float bfu(unsigned short u) {
    return __uint_as_float(((unsigned)u) << 16);
}

// inv_freq[j] = 10000^(-2j/32) = 10^(-j/4)
__device__ const float c_invf[16] = {
    1.0f, 0.5623413251903491f, 0.31622776601683794f, 0.17782794100389228f,
    0.1f, 0.05623413251903491f, 0.031622776601683791f, 0.017782794100389228f,
    0.01f, 0.005623413251903491f, 0.0031622776601683794f, 0.0017782794100389228f,
    0.001f, 0.0005623413251903491f, 0.00031622776601683794f, 0.00017782794100389227f
};

// --- embed (+ compose in 2 blocks, + edge-count in trailing blocks) --------
__global__ __launch_bounds__(256) void k_embed(
    const float* __restrict__ x, const float* __restrict__ W,
    const float* __restrict__ b, float* __restrict__ H, int N, int nbMain,
    int E, const int* __restrict__ dst, int* __restrict__ cnt,
    const float* __restrict__ Wsk1, const float* __restrict__ bsk1,
    const float* __restrict__ Wh1,  const float* __restrict__ bh1,
    const float* __restrict__ Wsk2, const float* __restrict__ bsk2,
    const float* __restrict__ Wh2,  const float* __restrict__ bh2,
    float* __restrict__ WCB)
{
    if (blockIdx.x >= nbMain + 2) {
        int e = (blockIdx.x - nbMain - 2) * 256 + threadIdx.x;
        if (e < E) atomicAdd(&cnt[dst[e]], 1);
        return;
    }
    if (blockIdx.x >= nbMain) {
        int lay = blockIdx.x - nbMain;
        const float* Wsk = lay ? Wsk2 : Wsk1;
        const float* bsk = lay ? bsk2 : bsk1;
        const float* Wh  = lay ? Wh2  : Wh1;
        const float* bh  = lay ? bh2  : bh1;
        float* o = WCB + lay * 1056;
        for (int i = threadIdx.x; i < D32 * D32 + D32; i += 256) {
            if (i < D32 * D32) {
                int r = i >> 5, c = i & 31;
                float a = 0.f;
                for (int k = 0; k < HCH; ++k) a = fmaf(Wsk[r * HCH + k], Wh[k * D32 + c], a);
                o[i] = a;
            } else {
                int c = i - D32 * D32;
                float a = bh[c];
                for (int k = 0; k < HCH; ++k) a = fmaf(bsk[k], Wh[k * D32 + c], a);
                o[1024 + c] = a;
            }
        }
        return;
    }
    __shared__ float xs[8][64];
    __shared__ float ws[INCH * D32];
    int row0 = blockIdx.x * 8;
    for (int i = threadIdx.x; i < INCH * D32; i += 256) ws[i] = W[i];
    for (int i = threadIdx.x; i < 8 * INCH; i += 256) {
        int r = i / INCH, cc = i % INCH;
        int gr = row0 + r;
        xs[r][cc] = (gr < N) ? x[(size_t)gr * INCH + cc] : 0.f;
    }
    __syncthreads();
    int lr = threadIdx.x >> 5, c = threadIdx.x & 31;
    int row = row0 + lr;
    if (row >= N) return;
    float acc = b[c];
#pragma unroll
    for (int k = 0; k < INCH; ++k) acc = fmaf(xs[lr][k], ws[k * D32 + c], acc);
    float phase = (float)row * c_invf[c >> 1];
    float pe = (c & 1) ? cosf(phase) : sinf(phase);
    H[(size_t)row * D32 + c] = acc + pe;
}

// --- CSR build -------------------------------------------------------------
__global__ void k_scan1(const int* __restrict__ cnt, int* __restrict__ rowptr,
                        int* __restrict__ partials, float* __restrict__ DIS, int N)
{
    __shared__ int s[256];
    int g = blockIdx.x * 256 + threadIdx.x;
    int myc = (g < N) ? cnt[g] : 0;
    if (g < N) DIS[g] = rsqrtf((float)myc + 1.0f);
    s[threadIdx.x] = myc;
    __syncthreads();
    for (int off = 1; off < 256; off <<= 1) {
        int t = (threadIdx.x >= off) ? s[threadIdx.x - off] : 0;
        __syncthreads();
        s[threadIdx.x] += t;
        __syncthreads();
    }
    if (g < N) rowptr[g + 1] = s[threadIdx.x];
    if (threadIdx.x == 255) partials[blockIdx.x] = s[255];
}
__global__ void k_scan2(int* __restrict__ partials, int nb) {
    __shared__ int s[256];
    int t = threadIdx.x;
    s[t] = (t < nb) ? partials[t] : 0;
    __syncthreads();
    for (int off = 1; off < 256; off <<= 1) {
        int v = (t >= off) ? s[t - off] : 0;
        __syncthreads();
        s[t] += v;
        __syncthreads();
    }
    partials[t] = (t == 0) ? 0 : s[t - 1];  // exclusive
}
__global__ void k_scan3b(int* __restrict__ rowptr, const int* __restrict__ partials,
                         int* __restrict__ cur, int N)
{
    int g = blockIdx.x * 256 + threadIdx.x;
    int add = partials[blockIdx.x];
    int oldprev = 0;
    if (g < N && threadIdx.x > 0) oldprev = rowptr[g];
    __syncthreads();
    if (g < N) {
        rowptr[g + 1] += add;
        cur[g] = (threadIdx.x == 0) ? add : oldprev + add;
        if (g == 0) rowptr[0] = 0;
    }
}
__global__ void k_fill(const int* __restrict__ src, const int* __restrict__ dst,
                       int* __restrict__ cur, int* __restrict__ colsrc, int E)
{
    int e = blockIdx.x * 256 + threadIdx.x;
    if (e < E) {
        int p = atomicAdd(&cur[dst[e]], 1);
        colsrc[p] = src[e];
    }
}

// --- Q (bf16, pre-scaled), K/V (bf16, per-lane [4K|4V]), SKIP=H@Wc+bc ------
// 16 rows per block: halves per-block weight re-reads from L2.
__global__ __launch_bounds__(256) void k_h32_to_kvqs(
    const float* __restrict__ Hm,
    const float* __restrict__ Wq, const float* __restrict__ bq,
    const float* __restrict__ Wk, const float* __restrict__ bk,
    const float* __restrict__ Wv, const float* __restrict__ bv,
    const float* __restrict__ WCBl,
    unsigned short* __restrict__ Qb, unsigned short* __restrict__ KV,
    float* __restrict__ SKIP, int N)
{
    __shared__ float hs[16][33];
    int row0 = blockIdx.x * 16;
    int c = threadIdx.x;
    for (int i = threadIdx.x; i < 16 * 32; i += 256) {
        int r = i >> 5, k = i & 31;
        int gr = row0 + r;
        hs[r][k] = (gr < N) ? Hm[(size_t)gr * D32 + k] : 0.f;
    }
    __syncthreads();
    float aQ[16], aK[16], aV[16], aS[16];
    float bQ = bq[c], bK = bk[c], bV = bv[c];
    float bS = (c < 32) ? WCBl[1024 + c] : 0.f;
#pragma unroll
    for (int r = 0; r < 16; ++r) { aQ[r] = bQ; aK[r] = bK; aV[r] = bV; aS[r] = bS; }
#pragma unroll 8
    for (int k = 0; k < 32; ++k) {
        float wq = Wq[k * HCH + c], wk = Wk[k * HCH + c], wv = Wv[k * HCH + c];
        float wc = (c < 32) ? WCBl[k * D32 + c] : 0.f;
#pragma unroll
        for (int r = 0; r < 16; ++r) {
            float h = hs[r][k];
            aQ[r] = fmaf(h, wq, aQ[r]);
            aK[r] = fmaf(h, wk, aK[r]);
            aV[r] = fmaf(h, wv, aV[r]);
            aS[r] = fmaf(h, wc, aS[r]);
        }
    }
    int hh = c >> 5, cc = c & 31, ss = cc >> 2, ii = cc & 3;
#pragma unroll
    for (int r = 0; r < 16; ++r) {
        int gr = row0 + r;
        if (gr < N) {
            Qb[(size_t)gr * HCH + c] = f2bf(aQ[r] * CSCALE);
            size_t kb = (size_t)gr * 512 + hh * 64 + ss * 8 + ii;
            KV[kb]     = f2bf(aK[r]);
            KV[kb + 4] = f2bf(aV[r]);
            if (c < 32) SKIP[(size_t)gr * D32 + c] = aS[r];
        }
    }
}

// --- fused attention: wave per dst node, group-of-4 double-buffered --------
// K-dot via v_dot2_f32_bf16 on packed bf16 pairs (Q stays packed).
#define PROC(A, PIDX)                                                        \
    {                                                                        \
        float t1, t;                                                         \
        asm("v_dot2_f32_bf16 %0, %1, %2, %3"                                 \
            : "=v"(t1) : "v"(A.y), "v"(qy), "v"(zf));                        \
        asm("v_dot2_f32_bf16 %0, %1, %2, %3"                                 \
            : "=v"(t) : "v"(A.x), "v"(qx), "v"(t1));                         \
        t += __shfl_xor(t, 1, 64);                                           \
        t += __shfl_xor(t, 2, 64);                                           \
        t += __shfl_xor(t, 4, 64);                                           \
        float wg = ((PIDX) <= pl) ? __builtin_amdgcn_exp2f(t) : 0.f;         \
        l += wg;                                                             \
        acc0 = fmaf(wg, __uint_as_float(A.z << 16), acc0);                   \
        acc1 = fmaf(wg, __uint_as_float(A.z & 0xffff0000u), acc1);           \
        acc2 = fmaf(wg, __uint_as_float(A.w << 16), acc2);                   \
        acc3 = fmaf(wg, __uint_as_float(A.w & 0xffff0000u), acc3);           \
    }
#define CLD(B, I) colsrc[min((B) + (I), pl)]

__global__ __launch_bounds__(256) void k_attn(
    const uint4* __restrict__ KV4, const uint2* __restrict__ Qb2,
    const float* __restrict__ SKIP, float* __restrict__ H,
    const int* __restrict__ rowptr, const int* __restrict__ colsrc,
    const float* __restrict__ Wh, int N)
{
    __shared__ float os[4][264];
    int w = threadIdx.x >> 6, lane = threadIdx.x & 63;
    int d = blockIdx.x * 4 + w;
    bool act = d < N;

    unsigned qx = 0u, qy = 0u;
    if (act) {
        uint2 qw = Qb2[(size_t)d * 64 + lane];
        qx = qw.x; qy = qw.y;
    }
    float zf = 0.f;

    float l = 0.f, acc0 = 0.f, acc1 = 0.f, acc2 = 0.f, acc3 = 0.f;
    if (act) {
        int p0 = rowptr[d], p1 = rowptr[d + 1];
        if (p1 > p0) {
            int pl = p1 - 1;
            int s0 = CLD(p0, 0), s1 = CLD(p0, 1), s2 = CLD(p0, 2), s3 = CLD(p0, 3);
            uint4 A0 = KV4[(size_t)s0 * 64 + lane];
            uint4 A1 = KV4[(size_t)s1 * 64 + lane];
            uint4 A2 = KV4[(size_t)s2 * 64 + lane];
            uint4 A3 = KV4[(size_t)s3 * 64 + lane];
#pragma unroll 2
            for (int base = p0; base < p1; base += 4) {
                int nb2 = base + 4;
                int t0 = CLD(nb2, 0), t1c = CLD(nb2, 1), t2c = CLD(nb2, 2), t3c = CLD(nb2, 3);
                uint4 B0 = KV4[(size_t)t0 * 64 + lane];
                uint4 B1 = KV4[(size_t)t1c * 64 + lane];
                uint4 B2 = KV4[(size_t)t2c * 64 + lane];
                uint4 B3 = KV4[(size_t)t3c * 64 + lane];
                PROC(A0, base)
                PROC(A1, base + 1)
                PROC(A2, base + 2)
                PROC(A3, base + 3)
                A0 = B0; A1 = B1; A2 = B2; A3 = B3;
            }
        }
        float inv = (l > 0.f) ? 1.f / l : 0.f;
        int gch = (lane >> 3) * 32 + (lane & 7) * 4;
        os[w][gch + 0] = acc0 * inv;
        os[w][gch + 1] = acc1 * inv;
        os[w][gch + 2] = acc2 * inv;
        os[w][gch + 3] = acc3 * inv;
    }
    __syncthreads();

    if (act) {
        int c = lane & 31, half = lane >> 5;
        float a2 = half ? 0.f : SKIP[(size_t)d * D32 + c];
        int kb = half * 128;
#pragma unroll 8
        for (int kk = 0; kk < 128; ++kk)
            a2 = fmaf(os[w][kb + kk], Wh[(kb + kk) * D32 + c], a2);
        a2 += __shfl_xor(a2, 32, 64);
        if (lane < 32) H[(size_t)d * D32 + c] = a2;
    }
}

// --- XW3 = DIS * (H @ Wg3), bf16 out ---------------------------------------
__global__ __launch_bounds__(256) void k_xw3(
    const float* __restrict__ X, const float* __restrict__ W,
    const float* __restrict__ DIS, unsigned short* __restrict__ O, int N)
{
    __shared__ float xs[8][33];
    __shared__ float ws[D32 * D32];
    int row0 = blockIdx.x * 8;
    int c = threadIdx.x & 31, lr = threadIdx.x >> 5;
    for (int i = threadIdx.x; i < D32 * D32; i += 256) ws[i] = W[i];
    {
        int gr = row0 + lr;
        xs[lr][c] = (gr < N) ? X[(size_t)gr * D32 + c] : 0.f;
    }
    __syncthreads();
    int row = row0 + lr;
    if (row >= N) return;
    float acc = 0.f;
#pragma unroll
    for (int k = 0; k < D32; ++k) acc = fmaf(xs[lr][k], ws[k * D32 + c], acc);
    O[(size_t)row * D32 + c] = f2bf(DIS[row] * acc);
}

// --- GCN layer 3: wave-per-node gather (even/odd halves); emits XW4 bf16 ---
__global__ __launch_bounds__(256) void k_gcn_f(
    const unsigned short* __restrict__ XWp, const float* __restrict__ DIS,
    const int* __restrict__ rowptr, const int* __restrict__ colsrc,
    const float* __restrict__ bg, const float* __restrict__ Wg4,
    unsigned short* __restrict__ XWout, int N)
{
    __shared__ float wgs[1024];
    for (int i = threadIdx.x; i < 1024; i += 256) wgs[i] = Wg4[i];
    __syncthreads();
    int w = threadIdx.x >> 6, lane = threadIdx.x & 63;
    int c = lane & 31, half = lane >> 5;
    int d = blockIdx.x * 4 + w;
    bool act = d < N;
    float acc = 0.f;
    if (act) {
        if (half == 0) acc = bfu(XWp[(size_t)d * D32 + c]);
        int p0 = rowptr[d], p1 = rowptr[d + 1];
        int i0 = p0 + half;
        if (i0 < p1) {
            int pl = p1 - 1;
            unsigned short uA = XWp[(size_t)colsrc[min(i0,     pl)] * D32 + c];
            unsigned short uB = XWp[(size_t)colsrc[min(i0 + 2, pl)] * D32 + c];
            unsigned short uC = XWp[(size_t)colsrc[min(i0 + 4, pl)] * D32 + c];
            unsigned short uD = XWp[(size_t)colsrc[min(i0 + 6, pl)] * D32 + c];
            for (int p = i0; p < p1; p += 2) {
                unsigned short uN = XWp[(size_t)colsrc[min(p + 8, pl)] * D32 + c];
                acc += bfu(uA);
                uA = uB; uB = uC; uC = uD; uD = uN;
            }
        }
    }
    acc += __shfl_xor(acc, 32, 64);
    float dd = 0.f, h3 = 0.f;
    if (act) { dd = DIS[d]; h3 = dd * acc + bg[c]; }
    float s = 0.f;
#pragma unroll
    for (int k = 0; k < 32; ++k)
        s = fmaf(__shfl(h3, k, 32), wgs[k * D32 + c], s);
    if (act && half == 0) XWout[(size_t)d * D32 + c] = f2bf(dd * s);
}

// --- GCN layer 4 (final): wave-per-node gather, fp32 out -------------------
__global__ __launch_bounds__(256) void k_gcn_last(
    const unsigned short* __restrict__ XWp, const float* __restrict__ DIS,
    const int* __restrict__ rowptr, const int* __restrict__ colsrc,
    const float* __restrict__ bg, float* __restrict__ Out, int N)
{
    int w = threadIdx.x >> 6, lane = threadIdx.x & 63;
    int c = lane & 31, half = lane >> 5;
    int d = blockIdx.x * 4 + w;
    if (d >= N) return;
    float acc = 0.f;
    if (half == 0) acc = bfu(XWp[(size_t)d * D32 + c]);
    int p0 = rowptr[d], p1 = rowptr[d + 1];
    int i0 = p0 + half;
    if (i0 < p1) {
        int pl = p1 - 1;
        unsigned short uA = XWp[(size_t)colsrc[min(i0,     pl)] * D32 + c];
        unsigned short uB = XWp[(size_t)colsrc[min(i0 + 2, pl)] * D32 + c];
        unsigned short uC = XWp[(size_t)colsrc[min(i0 + 4, pl)] * D32 + c];
        unsigned short uD = XWp[(size_t)colsrc[min(i0 + 6, pl)] * D32 + c];
        for (int p = i0; p < p1; p += 2) {
            unsigned short uN = XWp[(size_t)colsrc[min(p + 8, pl)] * D32 + c];
            acc += bfu(uA);
            uA = uB; uB = uC; uC = uD; uD = uN;
        }
    }
    acc += __shfl_xor(acc, 32, 64);
    if (half == 0) Out[(size_t)d * D32 + c] = DIS[d] * acc + bg[c];
}

// ---------------------------------------------------------------------------
extern "C" void kernel_launch(void* const* d_in, const int* in_sizes, int n_in,
                              void* d_out, int out_size, void* d_ws, size_t ws_size,
                              hipStream_t stream)
{
    const float* x  = (const float*)d_in[0];
    const int*   ei = (const int*)d_in[1];
    const int N = in_sizes[0] / INCH;
    const int E = in_sizes[1] / 2;
    const int* src = ei;
    const int* dst = ei + E;

    const float* W_embed = (const float*)d_in[2];
    const float* b_embed = (const float*)d_in[3];
    const float* Wg3 = (const float*)d_in[24];
    const float* bg3 = (const float*)d_in[25];
    const float* Wg4 = (const float*)d_in[26];
    const float* bg4 = (const float*)d_in[27];

    unsigned short* KV  = (unsigned short*)d_ws;        // N*512 bf16
    unsigned short* Qb  = KV + (size_t)N * 512;         // N*256 bf16
    float* H      = (float*)(Qb + (size_t)N * HCH);     // N*32 f32
    float* SKIP   = H + (size_t)N * D32;                // N*32 f32
    unsigned short* XW1 = (unsigned short*)(SKIP + (size_t)N * D32);  // N*32 bf16
    unsigned short* XW2 = XW1 + (size_t)N * D32;        // N*32 bf16
    int*   rowptr = (int*)(XW2 + (size_t)N * D32);      // N+1
    int*   colsrc = rowptr + (N + 1);                   // E
    int*   cursor = colsrc + E;                         // N
    int*   partials = cursor + N;                       // 256
    float* DIS    = (float*)(partials + 256);           // N
    float* WCB    = DIS + N;                            // 2*1056
    float* out    = (float*)d_out;

    const int nb8  = (N + 7) / 8;
    const int nb16 = (N + 15) / 16;
    const int nb4  = (N + 3) / 4;
    const int nbN  = (N + 255) / 256;
    const int nbE  = (E + 255) / 256;

    hipMemsetAsync(cursor, 0, (size_t)N * sizeof(int), stream);

    k_embed<<<nb8 + 2 + nbE, 256, 0, stream>>>(
        x, W_embed, b_embed, H, N, nb8, E, dst, cursor,
        (const float*)d_in[10], (const float*)d_in[11],
        (const float*)d_in[12], (const float*)d_in[13],
        (const float*)d_in[20], (const float*)d_in[21],
        (const float*)d_in[22], (const float*)d_in[23], WCB);

    k_scan1<<<nbN, 256, 0, stream>>>(cursor, rowptr, partials, DIS, N);
    k_scan2<<<1, 256, 0, stream>>>(partials, nbN);
    k_scan3b<<<nbN, 256, 0, stream>>>(rowptr, partials, cursor, N);
    k_fill<<<nbE, 256, 0, stream>>>(src, dst, cursor, colsrc, E);

    for (int layer = 0; layer < 2; ++layer) {
        int base = 4 + layer * 10;
        const float* Wq = (const float*)d_in[base + 0];
        const float* bq = (const float*)d_in[base + 1];
        const float* Wk = (const float*)d_in[base + 2];
        const float* bk = (const float*)d_in[base + 3];
        const float* Wv = (const float*)d_in[base + 4];
        const float* bv = (const float*)d_in[base + 5];
        const float* Wh = (const float*)d_in[base + 8];

        k_h32_to_kvqs<<<nb16, 256, 0, stream>>>(
            H, Wq, bq, Wk, bk, Wv, bv, WCB + layer * 1056, Qb, KV, SKIP, N);
        k_attn<<<nb4, 256, 0, stream>>>(
            (const uint4*)KV, (const uint2*)Qb, SKIP, H, rowptr, colsrc, Wh, N);
    }

    // XW3 = DIS * (H @ Wg3) in bf16, then GCN gathers
    k_xw3<<<nb8, 256, 0, stream>>>(H, Wg3, DIS, XW1, N);
    k_gcn_f<<<nb4, 256, 0, stream>>>(XW1, DIS, rowptr, colsrc, bg3, Wg4, XW2, N);
    k_gcn_last<<<nb4, 256, 0, stream>>>(XW2, DIS, rowptr, colsrc, bg4, out, N);
}

// Round 11
// 431.882 us; speedup vs baseline: 1.0791x; 1.0791x over previous
//
#include <hip/hip_runtime.h>
#include <cstddef>

// ---------------------------------------------------------------------------
// GNN forward: embed+posenc -> 2x TransformerConv(8 heads x 32) -> 2x GCNConv
// N=50000, E=400000, IN=63, D=32, HC=256.
// R11 = R9 (proven kvqs 8-row, GCN 8-node/block) + R10's measured attn win
// (v_dot2_f32_bf16 K-dot on packed Q, exp2 builtin).
// No-max softmax; CSR built once; no per-edge atomics anywhere.
// ---------------------------------------------------------------------------

#define NH 8
#define HCH 256
#define D32 32
#define INCH 63
#define CSCALE 0.25503485356f   // log2(e) / sqrt(32)

__device__ __forceinline__ unsigned short f2bf(float f) {
    unsigned u = __float_as_uint(f);
    u += 0x7fff + ((u >> 16) & 1);   // RNE
    return (unsigned short)(u >> 16);
}
__device__ __forceinline__ float bfu(unsigned short u) {
    return __uint_as_float(((unsigned)u) << 16);
}

// inv_freq[j] = 10000^(-2j/32) = 10^(-j/4)
__device__ const float c_invf[16] = {
    1.0f, 0.5623413251903491f, 0.31622776601683794f, 0.17782794100389228f,
    0.1f, 0.05623413251903491f, 0.031622776601683791f, 0.017782794100389228f,
    0.01f, 0.005623413251903491f, 0.0031622776601683794f, 0.0017782794100389228f,
    0.001f, 0.0005623413251903491f, 0.00031622776601683794f, 0.00017782794100389227f
};

// --- embed (+ compose in 2 blocks, + edge-count in trailing blocks) --------
__global__ __launch_bounds__(256) void k_embed(
    const float* __restrict__ x, const float* __restrict__ W,
    const float* __restrict__ b, float* __restrict__ H, int N, int nbMain,
    int E, const int* __restrict__ dst, int* __restrict__ cnt,
    const float* __restrict__ Wsk1, const float* __restrict__ bsk1,
    const float* __restrict__ Wh1,  const float* __restrict__ bh1,
    const float* __restrict__ Wsk2, const float* __restrict__ bsk2,
    const float* __restrict__ Wh2,  const float* __restrict__ bh2,
    float* __restrict__ WCB)
{
    if (blockIdx.x >= nbMain + 2) {
        int e = (blockIdx.x - nbMain - 2) * 256 + threadIdx.x;
        if (e < E) atomicAdd(&cnt[dst[e]], 1);
        return;
    }
    if (blockIdx.x >= nbMain) {
        int lay = blockIdx.x - nbMain;
        const float* Wsk = lay ? Wsk2 : Wsk1;
        const float* bsk = lay ? bsk2 : bsk1;
        const float* Wh  = lay ? Wh2  : Wh1;
        const float* bh  = lay ? bh2  : bh1;
        float* o = WCB + lay * 1056;
        for (int i = threadIdx.x; i < D32 * D32 + D32; i += 256) {
            if (i < D32 * D32) {
                int r = i >> 5, c = i & 31;
                float a = 0.f;
                for (int k = 0; k < HCH; ++k) a = fmaf(Wsk[r * HCH + k], Wh[k * D32 + c], a);
                o[i] = a;
            } else {
                int c = i - D32 * D32;
                float a = bh[c];
                for (int k = 0; k < HCH; ++k) a = fmaf(bsk[k], Wh[k * D32 + c], a);
                o[1024 + c] = a;
            }
        }
        return;
    }
    __shared__ float xs[8][64];
    __shared__ float ws[INCH * D32];
    int row0 = blockIdx.x * 8;
    for (int i = threadIdx.x; i < INCH * D32; i += 256) ws[i] = W[i];
    for (int i = threadIdx.x; i < 8 * INCH; i += 256) {
        int r = i / INCH, cc = i % INCH;
        int gr = row0 + r;
        xs[r][cc] = (gr < N) ? x[(size_t)gr * INCH + cc] : 0.f;
    }
    __syncthreads();
    int lr = threadIdx.x >> 5, c = threadIdx.x & 31;
    int row = row0 + lr;
    if (row >= N) return;
    float acc = b[c];
#pragma unroll
    for (int k = 0; k < INCH; ++k) acc = fmaf(xs[lr][k], ws[k * D32 + c], acc);
    float phase = (float)row * c_invf[c >> 1];
    float pe = (c & 1) ? cosf(phase) : sinf(phase);
    H[(size_t)row * D32 + c] = acc + pe;
}

// --- CSR build -------------------------------------------------------------
__global__ void k_scan1(const int* __restrict__ cnt, int* __restrict__ rowptr,
                        int* __restrict__ partials, float* __restrict__ DIS, int N)
{
    __shared__ int s[256];
    int g = blockIdx.x * 256 + threadIdx.x;
    int myc = (g < N) ? cnt[g] : 0;
    if (g < N) DIS[g] = rsqrtf((float)myc + 1.0f);
    s[threadIdx.x] = myc;
    __syncthreads();
    for (int off = 1; off < 256; off <<= 1) {
        int t = (threadIdx.x >= off) ? s[threadIdx.x - off] : 0;
        __syncthreads();
        s[threadIdx.x] += t;
        __syncthreads();
    }
    if (g < N) rowptr[g + 1] = s[threadIdx.x];
    if (threadIdx.x == 255) partials[blockIdx.x] = s[255];
}
__global__ void k_scan2(int* __restrict__ partials, int nb) {
    __shared__ int s[256];
    int t = threadIdx.x;
    s[t] = (t < nb) ? partials[t] : 0;
    __syncthreads();
    for (int off = 1; off < 256; off <<= 1) {
        int v = (t >= off) ? s[t - off] : 0;
        __syncthreads();
        s[t] += v;
        __syncthreads();
    }
    partials[t] = (t == 0) ? 0 : s[t - 1];  // exclusive
}
__global__ void k_scan3b(int* __restrict__ rowptr, const int* __restrict__ partials,
                         int* __restrict__ cur, int N)
{
    int g = blockIdx.x * 256 + threadIdx.x;
    int add = partials[blockIdx.x];
    int oldprev = 0;
    if (g < N && threadIdx.x > 0) oldprev = rowptr[g];
    __syncthreads();
    if (g < N) {
        rowptr[g + 1] += add;
        cur[g] = (threadIdx.x == 0) ? add : oldprev + add;
        if (g == 0) rowptr[0] = 0;
    }
}
__global__ void k_fill(const int* __restrict__ src, const int* __restrict__ dst,
                       int* __restrict__ cur, int* __restrict__ colsrc, int E)
{
    int e = blockIdx.x * 256 + threadIdx.x;
    if (e < E) {
        int p = atomicAdd(&cur[dst[e]], 1);
        colsrc[p] = src[e];
    }
}

// --- Q (bf16, pre-scaled), K/V (bf16, per-lane [4K|4V]), SKIP=H@Wc+bc ------
__global__ __launch_bounds__(256) void k_h32_to_kvqs(
    const float* __restrict__ Hm,
    const float* __restrict__ Wq, const float* __restrict__ bq,
    const float* __restrict__ Wk, const float* __restrict__ bk,
    const float* __restrict__ Wv, const float* __restrict__ bv,
    const float* __restrict__ WCBl,
    unsigned short* __restrict__ Qb, unsigned short* __restrict__ KV,
    float* __restrict__ SKIP, int N)
{
    __shared__ float hs[8][33];
    int row0 = blockIdx.x * 8;
    int c = threadIdx.x;
    {
        int r = threadIdx.x >> 5, k = threadIdx.x & 31;
        int gr = row0 + r;
        hs[r][k] = (gr < N) ? Hm[(size_t)gr * D32 + k] : 0.f;
    }
    __syncthreads();
    float aQ[8], aK[8], aV[8], aS[8];
    float bQ = bq[c], bK = bk[c], bV = bv[c];
    float bS = (c < 32) ? WCBl[1024 + c] : 0.f;
#pragma unroll
    for (int r = 0; r < 8; ++r) { aQ[r] = bQ; aK[r] = bK; aV[r] = bV; aS[r] = bS; }
#pragma unroll 8
    for (int k = 0; k < 32; ++k) {
        float wq = Wq[k * HCH + c], wk = Wk[k * HCH + c], wv = Wv[k * HCH + c];
        float wc = (c < 32) ? WCBl[k * D32 + c] : 0.f;
#pragma unroll
        for (int r = 0; r < 8; ++r) {
            float h = hs[r][k];
            aQ[r] = fmaf(h, wq, aQ[r]);
            aK[r] = fmaf(h, wk, aK[r]);
            aV[r] = fmaf(h, wv, aV[r]);
            aS[r] = fmaf(h, wc, aS[r]);
        }
    }
    int hh = c >> 5, cc = c & 31, ss = cc >> 2, ii = cc & 3;
#pragma unroll
    for (int r = 0; r < 8; ++r) {
        int gr = row0 + r;
        if (gr < N) {
            Qb[(size_t)gr * HCH + c] = f2bf(aQ[r] * CSCALE);
            size_t kb = (size_t)gr * 512 + hh * 64 + ss * 8 + ii;
            KV[kb]     = f2bf(aK[r]);
            KV[kb + 4] = f2bf(aV[r]);
            if (c < 32) SKIP[(size_t)gr * D32 + c] = aS[r];
        }
    }
}

// --- fused attention: wave per dst node, group-of-4 double-buffered --------
// K-dot via v_dot2_f32_bf16 on packed bf16 pairs (Q stays packed).
#define PROC(A, PIDX)                                                        \
    {                                                                        \
        float t1, t;                                                         \
        asm("v_dot2_f32_bf16 %0, %1, %2, %3"                                 \
            : "=v"(t1) : "v"(A.y), "v"(qy), "v"(zf));                        \
        asm("v_dot2_f32_bf16 %0, %1, %2, %3"                                 \
            : "=v"(t) : "v"(A.x), "v"(qx), "v"(t1));                         \
        t += __shfl_xor(t, 1, 64);                                           \
        t += __shfl_xor(t, 2, 64);                                           \
        t += __shfl_xor(t, 4, 64);                                           \
        float wg = ((PIDX) <= pl) ? __builtin_amdgcn_exp2f(t) : 0.f;         \
        l += wg;                                                             \
        acc0 = fmaf(wg, __uint_as_float(A.z << 16), acc0);                   \
        acc1 = fmaf(wg, __uint_as_float(A.z & 0xffff0000u), acc1);           \
        acc2 = fmaf(wg, __uint_as_float(A.w << 16), acc2);                   \
        acc3 = fmaf(wg, __uint_as_float(A.w & 0xffff0000u), acc3);           \
    }
#define CLD(B, I) colsrc[min((B) + (I), pl)]

__global__ __launch_bounds__(256) void k_attn(
    const uint4* __restrict__ KV4, const uint2* __restrict__ Qb2,
    const float* __restrict__ SKIP, float* __restrict__ H,
    const int* __restrict__ rowptr, const int* __restrict__ colsrc,
    const float* __restrict__ Wh, int N)
{
    __shared__ float os[4][264];
    int w = threadIdx.x >> 6, lane = threadIdx.x & 63;
    int d = blockIdx.x * 4 + w;
    bool act = d < N;

    unsigned qx = 0u, qy = 0u;
    if (act) {
        uint2 qw = Qb2[(size_t)d * 64 + lane];
        qx = qw.x; qy = qw.y;
    }
    float zf = 0.f;

    float l = 0.f, acc0 = 0.f, acc1 = 0.f, acc2 = 0.f, acc3 = 0.f;
    if (act) {
        int p0 = rowptr[d], p1 = rowptr[d + 1];
        if (p1 > p0) {
            int pl = p1 - 1;
            int s0 = CLD(p0, 0), s1 = CLD(p0, 1), s2 = CLD(p0, 2), s3 = CLD(p0, 3);
            uint4 A0 = KV4[(size_t)s0 * 64 + lane];
            uint4 A1 = KV4[(size_t)s1 * 64 + lane];
            uint4 A2 = KV4[(size_t)s2 * 64 + lane];
            uint4 A3 = KV4[(size_t)s3 * 64 + lane];
#pragma unroll 2
            for (int base = p0; base < p1; base += 4) {
                int nb2 = base + 4;
                int t0 = CLD(nb2, 0), t1c = CLD(nb2, 1), t2c = CLD(nb2, 2), t3c = CLD(nb2, 3);
                uint4 B0 = KV4[(size_t)t0 * 64 + lane];
                uint4 B1 = KV4[(size_t)t1c * 64 + lane];
                uint4 B2 = KV4[(size_t)t2c * 64 + lane];
                uint4 B3 = KV4[(size_t)t3c * 64 + lane];
                PROC(A0, base)
                PROC(A1, base + 1)
                PROC(A2, base + 2)
                PROC(A3, base + 3)
                A0 = B0; A1 = B1; A2 = B2; A3 = B3;
            }
        }
        float inv = (l > 0.f) ? 1.f / l : 0.f;
        int gch = (lane >> 3) * 32 + (lane & 7) * 4;
        os[w][gch + 0] = acc0 * inv;
        os[w][gch + 1] = acc1 * inv;
        os[w][gch + 2] = acc2 * inv;
        os[w][gch + 3] = acc3 * inv;
    }
    __syncthreads();

    if (act) {
        int c = lane & 31, half = lane >> 5;
        float a2 = half ? 0.f : SKIP[(size_t)d * D32 + c];
        int kb = half * 128;
#pragma unroll 8
        for (int kk = 0; kk < 128; ++kk)
            a2 = fmaf(os[w][kb + kk], Wh[(kb + kk) * D32 + c], a2);
        a2 += __shfl_xor(a2, 32, 64);
        if (lane < 32) H[(size_t)d * D32 + c] = a2;
    }
}

// --- XW3 = DIS * (H @ Wg3), bf16 out ---------------------------------------
__global__ __launch_bounds__(256) void k_xw3(
    const float* __restrict__ X, const float* __restrict__ W,
    const float* __restrict__ DIS, unsigned short* __restrict__ O, int N)
{
    __shared__ float xs[8][33];
    __shared__ float ws[D32 * D32];
    int row0 = blockIdx.x * 8;
    int c = threadIdx.x & 31, lr = threadIdx.x >> 5;
    for (int i = threadIdx.x; i < D32 * D32; i += 256) ws[i] = W[i];
    {
        int gr = row0 + lr;
        xs[lr][c] = (gr < N) ? X[(size_t)gr * D32 + c] : 0.f;
    }
    __syncthreads();
    int row = row0 + lr;
    if (row >= N) return;
    float acc = 0.f;
#pragma unroll
    for (int k = 0; k < D32; ++k) acc = fmaf(xs[lr][k], ws[k * D32 + c], acc);
    O[(size_t)row * D32 + c] = f2bf(DIS[row] * acc);
}

// --- GCN layer 3: gather bf16 XW rows; fused epilogue emits XW4 bf16 -------
__global__ __launch_bounds__(256) void k_gcn_f(
    const unsigned short* __restrict__ XWp, const float* __restrict__ DIS,
    const int* __restrict__ rowptr, const int* __restrict__ colsrc,
    const float* __restrict__ bg, const float* __restrict__ Wg4,
    unsigned short* __restrict__ XWout, int N)
{
    __shared__ float wgs[1024];
    for (int i = threadIdx.x; i < 1024; i += 256) wgs[i] = Wg4[i];
    __syncthreads();
    int g = threadIdx.x >> 5;
    int c = threadIdx.x & 31;
    int d = blockIdx.x * 8 + g;
    bool act = d < N;
    float dd = 0.f, h3 = 0.f;
    if (act) {
        float acc = bfu(XWp[(size_t)d * D32 + c]);
        int p0 = rowptr[d], p1 = rowptr[d + 1];
        if (p1 > p0) {
            int pl = p1 - 1;
            unsigned short uA = XWp[(size_t)CLD(p0, 0) * D32 + c];
            unsigned short uB = XWp[(size_t)CLD(p0, 1) * D32 + c];
            unsigned short uC = XWp[(size_t)CLD(p0, 2) * D32 + c];
            unsigned short uD = XWp[(size_t)CLD(p0, 3) * D32 + c];
#pragma unroll 4
            for (int p = p0; p < p1; ++p) {
                unsigned short uN = XWp[(size_t)CLD(p, 4) * D32 + c];
                acc += bfu(uA);
                uA = uB; uB = uC; uC = uD; uD = uN;
            }
        }
        dd = DIS[d];
        h3 = dd * acc + bg[c];
    }
    float s = 0.f;
#pragma unroll
    for (int k = 0; k < 32; ++k)
        s = fmaf(__shfl(h3, k, 32), wgs[k * D32 + c], s);
    if (act) XWout[(size_t)d * D32 + c] = f2bf(dd * s);
}

// --- GCN layer 4 (final): gather bf16, fp32 out ----------------------------
__global__ __launch_bounds__(256) void k_gcn_last(
    const unsigned short* __restrict__ XWp, const float* __restrict__ DIS,
    const int* __restrict__ rowptr, const int* __restrict__ colsrc,
    const float* __restrict__ bg, float* __restrict__ Out, int N)
{
    int g = threadIdx.x >> 5;
    int c = threadIdx.x & 31;
    int d = blockIdx.x * 8 + g;
    if (d >= N) return;
    float acc = bfu(XWp[(size_t)d * D32 + c]);
    int p0 = rowptr[d], p1 = rowptr[d + 1];
    if (p1 > p0) {
        int pl = p1 - 1;
        unsigned short uA = XWp[(size_t)CLD(p0, 0) * D32 + c];
        unsigned short uB = XWp[(size_t)CLD(p0, 1) * D32 + c];
        unsigned short uC = XWp[(size_t)CLD(p0, 2) * D32 + c];
        unsigned short uD = XWp[(size_t)CLD(p0, 3) * D32 + c];
#pragma unroll 4
        for (int p = p0; p < p1; ++p) {
            unsigned short uN = XWp[(size_t)CLD(p, 4) * D32 + c];
            acc += bfu(uA);
            uA = uB; uB = uC; uC = uD; uD = uN;
        }
    }
    Out[(size_t)d * D32 + c] = DIS[d] * acc + bg[c];
}

// ---------------------------------------------------------------------------
extern "C" void kernel_launch(void* const* d_in, const int* in_sizes, int n_in,
                              void* d_out, int out_size, void* d_ws, size_t ws_size,
                              hipStream_t stream)
{
    const float* x  = (const float*)d_in[0];
    const int*   ei = (const int*)d_in[1];
    const int N = in_sizes[0] / INCH;
    const int E = in_sizes[1] / 2;
    const int* src = ei;
    const int* dst = ei + E;

    const float* W_embed = (const float*)d_in[2];
    const float* b_embed = (const float*)d_in[3];
    const float* Wg3 = (const float*)d_in[24];
    const float* bg3 = (const float*)d_in[25];
    const float* Wg4 = (const float*)d_in[26];
    const float* bg4 = (const float*)d_in[27];

    unsigned short* KV  = (unsigned short*)d_ws;        // N*512 bf16
    unsigned short* Qb  = KV + (size_t)N * 512;         // N*256 bf16
    float* H      = (float*)(Qb + (size_t)N * HCH);     // N*32 f32
    float* SKIP   = H + (size_t)N * D32;                // N*32 f32
    unsigned short* XW1 = (unsigned short*)(SKIP + (size_t)N * D32);  // N*32 bf16
    unsigned short* XW2 = XW1 + (size_t)N * D32;        // N*32 bf16
    int*   rowptr = (int*)(XW2 + (size_t)N * D32);      // N+1
    int*   colsrc = rowptr + (N + 1);                   // E
    int*   cursor = colsrc + E;                         // N
    int*   partials = cursor + N;                       // 256
    float* DIS    = (float*)(partials + 256);           // N
    float* WCB    = DIS + N;                            // 2*1056
    float* out    = (float*)d_out;

    const int nb8 = (N + 7) / 8;
    const int nb4 = (N + 3) / 4;
    const int nbN = (N + 255) / 256;
    const int nbE = (E + 255) / 256;

    hipMemsetAsync(cursor, 0, (size_t)N * sizeof(int), stream);

    k_embed<<<nb8 + 2 + nbE, 256, 0, stream>>>(
        x, W_embed, b_embed, H, N, nb8, E, dst, cursor,
        (const float*)d_in[10], (const float*)d_in[11],
        (const float*)d_in[12], (const float*)d_in[13],
        (const float*)d_in[20], (const float*)d_in[21],
        (const float*)d_in[22], (const float*)d_in[23], WCB);

    k_scan1<<<nbN, 256, 0, stream>>>(cursor, rowptr, partials, DIS, N);
    k_scan2<<<1, 256, 0, stream>>>(partials, nbN);
    k_scan3b<<<nbN, 256, 0, stream>>>(rowptr, partials, cursor, N);
    k_fill<<<nbE, 256, 0, stream>>>(src, dst, cursor, colsrc, E);

    for (int layer = 0; layer < 2; ++layer) {
        int base = 4 + layer * 10;
        const float* Wq = (const float*)d_in[base + 0];
        const float* bq = (const float*)d_in[base + 1];
        const float* Wk = (const float*)d_in[base + 2];
        const float* bk = (const float*)d_in[base + 3];
        const float* Wv = (const float*)d_in[base + 4];
        const float* bv = (const float*)d_in[base + 5];
        const float* Wh = (const float*)d_in[base + 8];

        k_h32_to_kvqs<<<nb8, 256, 0, stream>>>(
            H, Wq, bq, Wk, bk, Wv, bv, WCB + layer * 1056, Qb, KV, SKIP, N);
        k_attn<<<nb4, 256, 0, stream>>>(
            (const uint4*)KV, (const uint2*)Qb, SKIP, H, rowptr, colsrc, Wh, N);
    }

    // XW3 = DIS * (H @ Wg3) in bf16, then GCN gathers
    k_xw3<<<nb8, 256, 0, stream>>>(H, Wg3, DIS, XW1, N);
    k_gcn_f<<<nb8, 256, 0, stream>>>(XW1, DIS, rowptr, colsrc, bg3, Wg4, XW2, N);
    k_gcn_last<<<nb8, 256, 0, stream>>>(XW2, DIS, rowptr, colsrc, bg4, out, N);
}

// Round 12
// 368.240 us; speedup vs baseline: 1.2655x; 1.1728x over previous
//
#include <hip/hip_runtime.h>
#include <cstddef>

// ---------------------------------------------------------------------------
// GNN forward: embed+posenc -> 2x TransformerConv(8 heads x 32) -> 2x GCNConv
// N=50000, E=400000, IN=63, D=32, HC=256.
// R12 = R11 + packed-bf16 dot2 projections: all weights pre-packed as bf16
// pairs (one-time, in embed's extra blocks), kvqs inner loop = v_dot2_f32_bf16
// (512 vs 1024 VALU), attn epilogue dot2 on packed os; scan2 merged into
// scan3b. No-max softmax; CSR built once; no per-edge atomics anywhere.
// ---------------------------------------------------------------------------

#define NH 8
#define HCH 256
#define D32 32
#define INCH 63
#define CSCALE 0.25503485356f   // log2(e) / sqrt(32)

__device__ __forceinline__ unsigned short f2bf(float f) {
    unsigned u = __float_as_uint(f);
    u += 0x7fff + ((u >> 16) & 1);   // RNE
    return (unsigned short)(u >> 16);
}
__device__ __forceinline__ float bfu(unsigned short u) {
    return __uint_as_float(((unsigned)u) << 16);
}
__device__ __forceinline__ unsigned packbf(float lo, float hi) {
    return (unsigned)f2bf(lo) | ((unsigned)f2bf(hi) << 16);
}
#define DOT2(acc, a, b) \
    asm("v_dot2_f32_bf16 %0, %1, %2, %0" : "+v"(acc) : "v"(a), "v"(b))

// inv_freq[j] = 10000^(-2j/32) = 10^(-j/4)
__device__ const float c_invf[16] = {
    1.0f, 0.5623413251903491f, 0.31622776601683794f, 0.17782794100389228f,
    0.1f, 0.05623413251903491f, 0.031622776601683791f, 0.017782794100389228f,
    0.01f, 0.005623413251903491f, 0.0031622776601683794f, 0.0017782794100389228f,
    0.001f, 0.0005623413251903491f, 0.00031622776601683794f, 0.00017782794100389227f
};

// --- embed + compose(2) + weight-pack(8) + edge-count(nbE) blocks ----------
__global__ __launch_bounds__(256) void k_embed(
    const float* __restrict__ x, const float* __restrict__ W,
    const float* __restrict__ b, float* __restrict__ H, int N, int nbMain,
    int E, const int* __restrict__ dst, int* __restrict__ cnt,
    const float* __restrict__ Wsk1, const float* __restrict__ bsk1,
    const float* __restrict__ Wh1,  const float* __restrict__ bh1,
    const float* __restrict__ Wsk2, const float* __restrict__ bsk2,
    const float* __restrict__ Wh2,  const float* __restrict__ bh2,
    const float* __restrict__ Wq1, const float* __restrict__ Wk1,
    const float* __restrict__ Wv1,
    const float* __restrict__ Wq2, const float* __restrict__ Wk2,
    const float* __restrict__ Wv2,
    float* __restrict__ WCB,
    unsigned* __restrict__ WQP, unsigned* __restrict__ WKP,
    unsigned* __restrict__ WVP, unsigned* __restrict__ WHP,
    unsigned* __restrict__ WCP)
{
    if (blockIdx.x >= nbMain + 10) {
        int e = (blockIdx.x - nbMain - 10) * 256 + threadIdx.x;
        if (e < E) atomicAdd(&cnt[dst[e]], 1);
        return;
    }
    if (blockIdx.x >= nbMain + 2) {
        // pack one weight matrix to bf16 pairs (pair over k = row index)
        int p = blockIdx.x - nbMain - 2;   // 0..7
        int lay = p >> 2, m = p & 3;
        const float* Ws; unsigned* dp; int k2n, nc;
        if (m == 0)      { Ws = lay ? Wq2 : Wq1; dp = WQP + lay * 4096; k2n = 16;  nc = 256; }
        else if (m == 1) { Ws = lay ? Wk2 : Wk1; dp = WKP + lay * 4096; k2n = 16;  nc = 256; }
        else if (m == 2) { Ws = lay ? Wv2 : Wv1; dp = WVP + lay * 4096; k2n = 16;  nc = 256; }
        else             { Ws = lay ? Wh2 : Wh1; dp = WHP + lay * 4096; k2n = 128; nc = 32;  }
        for (int i = threadIdx.x; i < k2n * nc; i += 256) {
            int k2 = i / nc, c = i % nc;
            dp[i] = packbf(Ws[(2 * k2) * nc + c], Ws[(2 * k2 + 1) * nc + c]);
        }
        return;
    }
    if (blockIdx.x >= nbMain) {
        // compose: Wc = Ws@Wh (32x32), bc = bs@Wh + bh; then pack Wc pairs
        int lay = blockIdx.x - nbMain;
        const float* Wsk = lay ? Wsk2 : Wsk1;
        const float* bsk = lay ? bsk2 : bsk1;
        const float* Wh  = lay ? Wh2  : Wh1;
        const float* bh  = lay ? bh2  : bh1;
        float* o = WCB + lay * 1056;
        for (int i = threadIdx.x; i < D32 * D32 + D32; i += 256) {
            if (i < D32 * D32) {
                int r = i >> 5, c = i & 31;
                float a = 0.f;
                for (int k = 0; k < HCH; ++k) a = fmaf(Wsk[r * HCH + k], Wh[k * D32 + c], a);
                o[i] = a;
            } else {
                int c = i - D32 * D32;
                float a = bh[c];
                for (int k = 0; k < HCH; ++k) a = fmaf(bsk[k], Wh[k * D32 + c], a);
                o[1024 + c] = a;
            }
        }
        __syncthreads();
        for (int i = threadIdx.x; i < 512; i += 256) {
            int k2 = i >> 5, c = i & 31;
            WCP[lay * 512 + i] = packbf(o[(2 * k2) * 32 + c], o[(2 * k2 + 1) * 32 + c]);
        }
        return;
    }
    __shared__ float xs[8][64];
    __shared__ float ws[INCH * D32];
    int row0 = blockIdx.x * 8;
    for (int i = threadIdx.x; i < INCH * D32; i += 256) ws[i] = W[i];
    for (int i = threadIdx.x; i < 8 * INCH; i += 256) {
        int r = i / INCH, cc = i % INCH;
        int gr = row0 + r;
        xs[r][cc] = (gr < N) ? x[(size_t)gr * INCH + cc] : 0.f;
    }
    __syncthreads();
    int lr = threadIdx.x >> 5, c = threadIdx.x & 31;
    int row = row0 + lr;
    if (row >= N) return;
    float acc = b[c];
#pragma unroll
    for (int k = 0; k < INCH; ++k) acc = fmaf(xs[lr][k], ws[k * D32 + c], acc);
    float phase = (float)row * c_invf[c >> 1];
    float pe = (c & 1) ? cosf(phase) : sinf(phase);
    H[(size_t)row * D32 + c] = acc + pe;
}

// --- CSR build -------------------------------------------------------------
__global__ void k_scan1(const int* __restrict__ cnt, int* __restrict__ rowptr,
                        int* __restrict__ partials, float* __restrict__ DIS, int N)
{
    __shared__ int s[256];
    int g = blockIdx.x * 256 + threadIdx.x;
    int myc = (g < N) ? cnt[g] : 0;
    if (g < N) DIS[g] = rsqrtf((float)myc + 1.0f);
    s[threadIdx.x] = myc;
    __syncthreads();
    for (int off = 1; off < 256; off <<= 1) {
        int t = (threadIdx.x >= off) ? s[threadIdx.x - off] : 0;
        __syncthreads();
        s[threadIdx.x] += t;
        __syncthreads();
    }
    if (g < N) rowptr[g + 1] = s[threadIdx.x];
    if (threadIdx.x == 255) partials[blockIdx.x] = s[255];
}
// scan3b: per-block prefix of partials computed in-block (scan2 merged)
__global__ void k_scan3b(int* __restrict__ rowptr, const int* __restrict__ partials,
                         int* __restrict__ cur, int N, int nb)
{
    __shared__ int s[256];
    int t = threadIdx.x;
    s[t] = (t < nb && t < (int)blockIdx.x) ? partials[t] : 0;
    __syncthreads();
    for (int off = 128; off > 0; off >>= 1) {
        if (t < off) s[t] += s[t + off];
        __syncthreads();
    }
    int add = s[0];
    int g = blockIdx.x * 256 + t;
    int oldprev = 0;
    if (g < N && t > 0) oldprev = rowptr[g];
    __syncthreads();
    if (g < N) {
        rowptr[g + 1] += add;
        cur[g] = (t == 0) ? add : oldprev + add;
        if (g == 0) rowptr[0] = 0;
    }
}
__global__ void k_fill(const int* __restrict__ src, const int* __restrict__ dst,
                       int* __restrict__ cur, int* __restrict__ colsrc, int E)
{
    int e = blockIdx.x * 256 + threadIdx.x;
    if (e < E) {
        int p = atomicAdd(&cur[dst[e]], 1);
        colsrc[p] = src[e];
    }
}

// --- Q/K/V/SKIP projections via packed bf16 dot2 ---------------------------
__global__ __launch_bounds__(256) void k_h32_to_kvqs(
    const float* __restrict__ Hm,
    const unsigned* __restrict__ WqP, const float* __restrict__ bq,
    const unsigned* __restrict__ WkP, const float* __restrict__ bk,
    const unsigned* __restrict__ WvP, const float* __restrict__ bv,
    const unsigned* __restrict__ WcP, const float* __restrict__ WCBl,
    unsigned short* __restrict__ Qb, unsigned short* __restrict__ KV,
    float* __restrict__ SKIP, int N)
{
    __shared__ unsigned hp[8][17];
    int row0 = blockIdx.x * 8;
    int c = threadIdx.x;
    if (threadIdx.x < 128) {
        int r = threadIdx.x >> 4, k2 = threadIdx.x & 15;
        int gr = row0 + r;
        float2 hv = (gr < N) ? ((const float2*)Hm)[(size_t)gr * 16 + k2]
                             : make_float2(0.f, 0.f);
        hp[r][k2] = packbf(hv.x, hv.y);
    }
    __syncthreads();
    float aQ[8], aK[8], aV[8], aS[8];
    float bQ = bq[c], bK = bk[c], bV = bv[c];
    float bS = (c < 32) ? WCBl[1024 + c] : 0.f;
#pragma unroll
    for (int r = 0; r < 8; ++r) { aQ[r] = bQ; aK[r] = bK; aV[r] = bV; aS[r] = bS; }
#pragma unroll 4
    for (int k2 = 0; k2 < 16; ++k2) {
        unsigned wq = WqP[k2 * 256 + c];
        unsigned wk = WkP[k2 * 256 + c];
        unsigned wv = WvP[k2 * 256 + c];
        unsigned wc = (c < 32) ? WcP[k2 * 32 + c] : 0u;
#pragma unroll
        for (int r = 0; r < 8; ++r) {
            unsigned h = hp[r][k2];
            DOT2(aQ[r], h, wq);
            DOT2(aK[r], h, wk);
            DOT2(aV[r], h, wv);
            DOT2(aS[r], h, wc);
        }
    }
    int hh = c >> 5, cc = c & 31, ss = cc >> 2, ii = cc & 3;
#pragma unroll
    for (int r = 0; r < 8; ++r) {
        int gr = row0 + r;
        if (gr < N) {
            Qb[(size_t)gr * HCH + c] = f2bf(aQ[r] * CSCALE);
            size_t kb = (size_t)gr * 512 + hh * 64 + ss * 8 + ii;
            KV[kb]     = f2bf(aK[r]);
            KV[kb + 4] = f2bf(aV[r]);
            if (c < 32) SKIP[(size_t)gr * D32 + c] = aS[r];
        }
    }
}

// --- fused attention: wave per dst node, group-of-4 double-buffered --------
#define PROC(A, PIDX)                                                        \
    {                                                                        \
        float t1, t;                                                         \
        asm("v_dot2_f32_bf16 %0, %1, %2, %3"                                 \
            : "=v"(t1) : "v"(A.y), "v"(qy), "v"(zf));                        \
        asm("v_dot2_f32_bf16 %0, %1, %2, %3"                                 \
            : "=v"(t) : "v"(A.x), "v"(qx), "v"(t1));                         \
        t += __shfl_xor(t, 1, 64);                                           \
        t += __shfl_xor(t, 2, 64);                                           \
        t += __shfl_xor(t, 4, 64);                                           \
        float wg = ((PIDX) <= pl) ? __builtin_amdgcn_exp2f(t) : 0.f;         \
        l += wg;                                                             \
        acc0 = fmaf(wg, __uint_as_float(A.z << 16), acc0);                   \
        acc1 = fmaf(wg, __uint_as_float(A.z & 0xffff0000u), acc1);           \
        acc2 = fmaf(wg, __uint_as_float(A.w << 16), acc2);                   \
        acc3 = fmaf(wg, __uint_as_float(A.w & 0xffff0000u), acc3);           \
    }
#define CLD(B, I) colsrc[min((B) + (I), pl)]

__global__ __launch_bounds__(256) void k_attn(
    const uint4* __restrict__ KV4, const uint2* __restrict__ Qb2,
    const float* __restrict__ SKIP, float* __restrict__ H,
    const int* __restrict__ rowptr, const int* __restrict__ colsrc,
    const unsigned* __restrict__ WhP, int N)
{
    __shared__ unsigned osp[4][136];
    int w = threadIdx.x >> 6, lane = threadIdx.x & 63;
    int d = blockIdx.x * 4 + w;
    bool act = d < N;

    unsigned qx = 0u, qy = 0u;
    if (act) {
        uint2 qw = Qb2[(size_t)d * 64 + lane];
        qx = qw.x; qy = qw.y;
    }
    float zf = 0.f;

    float l = 0.f, acc0 = 0.f, acc1 = 0.f, acc2 = 0.f, acc3 = 0.f;
    if (act) {
        int p0 = rowptr[d], p1 = rowptr[d + 1];
        if (p1 > p0) {
            int pl = p1 - 1;
            int s0 = CLD(p0, 0), s1 = CLD(p0, 1), s2 = CLD(p0, 2), s3 = CLD(p0, 3);
            uint4 A0 = KV4[(size_t)s0 * 64 + lane];
            uint4 A1 = KV4[(size_t)s1 * 64 + lane];
            uint4 A2 = KV4[(size_t)s2 * 64 + lane];
            uint4 A3 = KV4[(size_t)s3 * 64 + lane];
#pragma unroll 2
            for (int base = p0; base < p1; base += 4) {
                int nb2 = base + 4;
                int t0 = CLD(nb2, 0), t1c = CLD(nb2, 1), t2c = CLD(nb2, 2), t3c = CLD(nb2, 3);
                uint4 B0 = KV4[(size_t)t0 * 64 + lane];
                uint4 B1 = KV4[(size_t)t1c * 64 + lane];
                uint4 B2 = KV4[(size_t)t2c * 64 + lane];
                uint4 B3 = KV4[(size_t)t3c * 64 + lane];
                PROC(A0, base)
                PROC(A1, base + 1)
                PROC(A2, base + 2)
                PROC(A3, base + 3)
                A0 = B0; A1 = B1; A2 = B2; A3 = B3;
            }
        }
        float inv = (l > 0.f) ? 1.f / l : 0.f;
        int g2 = (lane >> 3) * 16 + (lane & 7) * 2;
        osp[w][g2]     = packbf(acc0 * inv, acc1 * inv);
        osp[w][g2 + 1] = packbf(acc2 * inv, acc3 * inv);
    }
    __syncthreads();

    if (act) {
        int c = lane & 31, half = lane >> 5;
        float a2 = half ? 0.f : SKIP[(size_t)d * D32 + c];
        int kb2 = half * 64;
#pragma unroll 8
        for (int kk = 0; kk < 64; ++kk) {
            unsigned o = osp[w][kb2 + kk];
            unsigned wh = WhP[(kb2 + kk) * 32 + c];
            DOT2(a2, o, wh);
        }
        a2 += __shfl_xor(a2, 32, 64);
        if (lane < 32) H[(size_t)d * D32 + c] = a2;
    }
}

// --- XW3 = DIS * (H @ Wg3), bf16 out ---------------------------------------
__global__ __launch_bounds__(256) void k_xw3(
    const float* __restrict__ X, const float* __restrict__ W,
    const float* __restrict__ DIS, unsigned short* __restrict__ O, int N)
{
    __shared__ float xs[8][33];
    __shared__ float ws[D32 * D32];
    int row0 = blockIdx.x * 8;
    int c = threadIdx.x & 31, lr = threadIdx.x >> 5;
    for (int i = threadIdx.x; i < D32 * D32; i += 256) ws[i] = W[i];
    {
        int gr = row0 + lr;
        xs[lr][c] = (gr < N) ? X[(size_t)gr * D32 + c] : 0.f;
    }
    __syncthreads();
    int row = row0 + lr;
    if (row >= N) return;
    float acc = 0.f;
#pragma unroll
    for (int k = 0; k < D32; ++k) acc = fmaf(xs[lr][k], ws[k * D32 + c], acc);
    O[(size_t)row * D32 + c] = f2bf(DIS[row] * acc);
}

// --- GCN layer 3: gather bf16 XW rows; fused epilogue emits XW4 bf16 -------
__global__ __launch_bounds__(256) void k_gcn_f(
    const unsigned short* __restrict__ XWp, const float* __restrict__ DIS,
    const int* __restrict__ rowptr, const int* __restrict__ colsrc,
    const float* __restrict__ bg, const float* __restrict__ Wg4,
    unsigned short* __restrict__ XWout, int N)
{
    __shared__ float wgs[1024];
    for (int i = threadIdx.x; i < 1024; i += 256) wgs[i] = Wg4[i];
    __syncthreads();
    int g = threadIdx.x >> 5;
    int c = threadIdx.x & 31;
    int d = blockIdx.x * 8 + g;
    bool act = d < N;
    float dd = 0.f, h3 = 0.f;
    if (act) {
        float acc = bfu(XWp[(size_t)d * D32 + c]);
        int p0 = rowptr[d], p1 = rowptr[d + 1];
        if (p1 > p0) {
            int pl = p1 - 1;
            unsigned short uA = XWp[(size_t)CLD(p0, 0) * D32 + c];
            unsigned short uB = XWp[(size_t)CLD(p0, 1) * D32 + c];
            unsigned short uC = XWp[(size_t)CLD(p0, 2) * D32 + c];
            unsigned short uD = XWp[(size_t)CLD(p0, 3) * D32 + c];
#pragma unroll 4
            for (int p = p0; p < p1; ++p) {
                unsigned short uN = XWp[(size_t)CLD(p, 4) * D32 + c];
                acc += bfu(uA);
                uA = uB; uB = uC; uC = uD; uD = uN;
            }
        }
        dd = DIS[d];
        h3 = dd * acc + bg[c];
    }
    float s = 0.f;
#pragma unroll
    for (int k = 0; k < 32; ++k)
        s = fmaf(__shfl(h3, k, 32), wgs[k * D32 + c], s);
    if (act) XWout[(size_t)d * D32 + c] = f2bf(dd * s);
}

// --- GCN layer 4 (final): gather bf16, fp32 out ----------------------------
__global__ __launch_bounds__(256) void k_gcn_last(
    const unsigned short* __restrict__ XWp, const float* __restrict__ DIS,
    const int* __restrict__ rowptr, const int* __restrict__ colsrc,
    const float* __restrict__ bg, float* __restrict__ Out, int N)
{
    int g = threadIdx.x >> 5;
    int c = threadIdx.x & 31;
    int d = blockIdx.x * 8 + g;
    if (d >= N) return;
    float acc = bfu(XWp[(size_t)d * D32 + c]);
    int p0 = rowptr[d], p1 = rowptr[d + 1];
    if (p1 > p0) {
        int pl = p1 - 1;
        unsigned short uA = XWp[(size_t)CLD(p0, 0) * D32 + c];
        unsigned short uB = XWp[(size_t)CLD(p0, 1) * D32 + c];
        unsigned short uC = XWp[(size_t)CLD(p0, 2) * D32 + c];
        unsigned short uD = XWp[(size_t)CLD(p0, 3) * D32 + c];
#pragma unroll 4
        for (int p = p0; p < p1; ++p) {
            unsigned short uN = XWp[(size_t)CLD(p, 4) * D32 + c];
            acc += bfu(uA);
            uA = uB; uB = uC; uC = uD; uD = uN;
        }
    }
    Out[(size_t)d * D32 + c] = DIS[d] * acc + bg[c];
}

// ---------------------------------------------------------------------------
extern "C" void kernel_launch(void* const* d_in, const int* in_sizes, int n_in,
                              void* d_out, int out_size, void* d_ws, size_t ws_size,
                              hipStream_t stream)
{
    const float* x  = (const float*)d_in[0];
    const int*   ei = (const int*)d_in[1];
    const int N = in_sizes[0] / INCH;
    const int E = in_sizes[1] / 2;
    const int* src = ei;
    const int* dst = ei + E;

    const float* W_embed = (const float*)d_in[2];
    const float* b_embed = (const float*)d_in[3];
    const float* Wg3 = (const float*)d_in[24];
    const float* bg3 = (const float*)d_in[25];
    const float* Wg4 = (const float*)d_in[26];
    const float* bg4 = (const float*)d_in[27];

    unsigned short* KV  = (unsigned short*)d_ws;        // N*512 bf16
    unsigned short* Qb  = KV + (size_t)N * 512;         // N*256 bf16
    float* H      = (float*)(Qb + (size_t)N * HCH);     // N*32 f32
    float* SKIP   = H + (size_t)N * D32;                // N*32 f32
    unsigned short* XW1 = (unsigned short*)(SKIP + (size_t)N * D32);  // N*32 bf16
    unsigned short* XW2 = XW1 + (size_t)N * D32;        // N*32 bf16
    int*   rowptr = (int*)(XW2 + (size_t)N * D32);      // N+1
    int*   colsrc = rowptr + (N + 1);                   // E
    int*   cursor = colsrc + E;                         // N
    int*   partials = cursor + N;                       // 256
    float* DIS    = (float*)(partials + 256);           // N
    float* WCB    = DIS + N;                            // 2*1056
    unsigned* WQP = (unsigned*)(WCB + 2 * 1056);        // 2*4096
    unsigned* WKP = WQP + 2 * 4096;                     // 2*4096
    unsigned* WVP = WKP + 2 * 4096;                     // 2*4096
    unsigned* WHP = WVP + 2 * 4096;                     // 2*4096
    unsigned* WCP = WHP + 2 * 4096;                     // 2*512
    float* out    = (float*)d_out;

    const int nb8 = (N + 7) / 8;
    const int nb4 = (N + 3) / 4;
    const int nbN = (N + 255) / 256;
    const int nbE = (E + 255) / 256;

    hipMemsetAsync(cursor, 0, (size_t)N * sizeof(int), stream);

    k_embed<<<nb8 + 10 + nbE, 256, 0, stream>>>(
        x, W_embed, b_embed, H, N, nb8, E, dst, cursor,
        (const float*)d_in[10], (const float*)d_in[11],
        (const float*)d_in[12], (const float*)d_in[13],
        (const float*)d_in[20], (const float*)d_in[21],
        (const float*)d_in[22], (const float*)d_in[23],
        (const float*)d_in[4],  (const float*)d_in[6],  (const float*)d_in[8],
        (const float*)d_in[14], (const float*)d_in[16], (const float*)d_in[18],
        WCB, WQP, WKP, WVP, WHP, WCP);

    k_scan1<<<nbN, 256, 0, stream>>>(cursor, rowptr, partials, DIS, N);
    k_scan3b<<<nbN, 256, 0, stream>>>(rowptr, partials, cursor, N, nbN);
    k_fill<<<nbE, 256, 0, stream>>>(src, dst, cursor, colsrc, E);

    for (int layer = 0; layer < 2; ++layer) {
        int base = 4 + layer * 10;
        const float* bq = (const float*)d_in[base + 1];
        const float* bk = (const float*)d_in[base + 3];
        const float* bv = (const float*)d_in[base + 5];

        k_h32_to_kvqs<<<nb8, 256, 0, stream>>>(
            H,
            WQP + layer * 4096, bq,
            WKP + layer * 4096, bk,
            WVP + layer * 4096, bv,
            WCP + layer * 512, WCB + layer * 1056,
            Qb, KV, SKIP, N);
        k_attn<<<nb4, 256, 0, stream>>>(
            (const uint4*)KV, (const uint2*)Qb, SKIP, H, rowptr, colsrc,
            WHP + layer * 4096, N);
    }

    // XW3 = DIS * (H @ Wg3) in bf16, then GCN gathers
    k_xw3<<<nb8, 256, 0, stream>>>(H, Wg3, DIS, XW1, N);
    k_gcn_f<<<nb8, 256, 0, stream>>>(XW1, DIS, rowptr, colsrc, bg3, Wg4, XW2, N);
    k_gcn_last<<<nb8, 256, 0, stream>>>(XW2, DIS, rowptr, colsrc, bg4, out, N);
}

// Round 13
// 354.329 us; speedup vs baseline: 1.3152x; 1.0393x over previous
//
#include <hip/hip_runtime.h>
#include <cstddef>

// ---------------------------------------------------------------------------
// GNN forward: embed+posenc -> 2x TransformerConv(8 heads x 32) -> 2x GCNConv
// N=50000, E=400000, IN=63, D=32, HC=256.
// R13 = R12 + compose rewritten as LDS-tiled mini-GEMM (kills the 2-block
// serial tail that made k_embed 77us at 9% VALUBusy).
// Packed-bf16 dot2 projections; no-max softmax; CSR once; no edge atomics.
// ---------------------------------------------------------------------------

#define NH 8
#define HCH 256
#define D32 32
#define INCH 63
#define CSCALE 0.25503485356f   // log2(e) / sqrt(32)

__device__ __forceinline__ unsigned short f2bf(float f) {
    unsigned u = __float_as_uint(f);
    u += 0x7fff + ((u >> 16) & 1);   // RNE
    return (unsigned short)(u >> 16);
}
__device__ __forceinline__ float bfu(unsigned short u) {
    return __uint_as_float(((unsigned)u) << 16);
}
__device__ __forceinline__ unsigned packbf(float lo, float hi) {
    return (unsigned)f2bf(lo) | ((unsigned)f2bf(hi) << 16);
}
#define DOT2(acc, a, b) \
    asm("v_dot2_f32_bf16 %0, %1, %2, %0" : "+v"(acc) : "v"(a), "v"(b))

// inv_freq[j] = 10000^(-2j/32) = 10^(-j/4)
__device__ const float c_invf[16] = {
    1.0f, 0.5623413251903491f, 0.31622776601683794f, 0.17782794100389228f,
    0.1f, 0.05623413251903491f, 0.031622776601683791f, 0.017782794100389228f,
    0.01f, 0.005623413251903491f, 0.0031622776601683794f, 0.0017782794100389228f,
    0.001f, 0.0005623413251903491f, 0.00031622776601683794f, 0.00017782794100389227f
};

// --- embed + compose(2, LDS-tiled) + weight-pack(8) + edge-count blocks ----
__global__ __launch_bounds__(256) void k_embed(
    const float* __restrict__ x, const float* __restrict__ W,
    const float* __restrict__ b, float* __restrict__ H, int N, int nbMain,
    int E, const int* __restrict__ dst, int* __restrict__ cnt,
    const float* __restrict__ Wsk1, const float* __restrict__ bsk1,
    const float* __restrict__ Wh1,  const float* __restrict__ bh1,
    const float* __restrict__ Wsk2, const float* __restrict__ bsk2,
    const float* __restrict__ Wh2,  const float* __restrict__ bh2,
    const float* __restrict__ Wq1, const float* __restrict__ Wk1,
    const float* __restrict__ Wv1,
    const float* __restrict__ Wq2, const float* __restrict__ Wk2,
    const float* __restrict__ Wv2,
    float* __restrict__ WCB,
    unsigned* __restrict__ WQP, unsigned* __restrict__ WKP,
    unsigned* __restrict__ WVP, unsigned* __restrict__ WHP,
    unsigned* __restrict__ WCP)
{
    __shared__ float smem[4352];   // union: main {xs 512, ws 2016} / compose {A 2048, B 2048, part 256}
    int tid = threadIdx.x;

    if (blockIdx.x >= nbMain + 10) {
        int e = (blockIdx.x - nbMain - 10) * 256 + tid;
        if (e < E) atomicAdd(&cnt[dst[e]], 1);
        return;
    }
    if (blockIdx.x >= nbMain + 2) {
        // pack one weight matrix to bf16 pairs (pair over k = row index)
        int p = blockIdx.x - nbMain - 2;   // 0..7
        int lay = p >> 2, m = p & 3;
        const float* Ws; unsigned* dp; int k2n, nc;
        if (m == 0)      { Ws = lay ? Wq2 : Wq1; dp = WQP + lay * 4096; k2n = 16;  nc = 256; }
        else if (m == 1) { Ws = lay ? Wk2 : Wk1; dp = WKP + lay * 4096; k2n = 16;  nc = 256; }
        else if (m == 2) { Ws = lay ? Wv2 : Wv1; dp = WVP + lay * 4096; k2n = 16;  nc = 256; }
        else             { Ws = lay ? Wh2 : Wh1; dp = WHP + lay * 4096; k2n = 128; nc = 32;  }
        for (int i = tid; i < k2n * nc; i += 256) {
            int k2 = i / nc, c = i % nc;
            dp[i] = packbf(Ws[(2 * k2) * nc + c], Ws[(2 * k2 + 1) * nc + c]);
        }
        return;
    }
    if (blockIdx.x >= nbMain) {
        // compose: Wc = Ws@Wh (32x32), bc = bs@Wh + bh -- LDS-tiled GEMM
        int lay = blockIdx.x - nbMain;
        const float* Wsk = lay ? Wsk2 : Wsk1;
        const float* bsk = lay ? bsk2 : bsk1;
        const float* Wh  = lay ? Wh2  : Wh1;
        const float* bh  = lay ? bh2  : bh1;
        float* o = WCB + lay * 1056;
        float* At = smem;            // [32][64]
        float* Bt = smem + 2048;     // [64][32]
        float* part = smem + 4096;   // [256]

        int r4 = tid >> 5, c4 = tid & 31;          // output (r4+8j, c4)? no: i=tid+j*256
        float acc[4] = {0.f, 0.f, 0.f, 0.f};
        for (int kt = 0; kt < 4; ++kt) {
            for (int i = tid; i < 2048; i += 256) {
                int r = i >> 6, kk = i & 63;
                At[i] = Wsk[r * HCH + kt * 64 + kk];
            }
            for (int i = tid; i < 2048; i += 256) {
                int kk = i >> 5, c = i & 31;
                Bt[i] = Wh[(kt * 64 + kk) * D32 + c];
            }
            __syncthreads();
#pragma unroll
            for (int j = 0; j < 4; ++j) {
                int i = tid + j * 256;
                int r = i >> 5, c = i & 31;
                float a = acc[j];
#pragma unroll 8
                for (int kk = 0; kk < 64; ++kk)
                    a = fmaf(At[r * 64 + kk], Bt[kk * 32 + c], a);
                acc[j] = a;
            }
            __syncthreads();
        }
#pragma unroll
        for (int j = 0; j < 4; ++j) o[tid + j * 256] = acc[j];
        // bias: part[t] over 8 k-slices of 32
        {
            int ks = tid >> 5;
            float bp = 0.f;
#pragma unroll 8
            for (int kk = 0; kk < 32; ++kk) {
                int k = ks * 32 + kk;
                bp = fmaf(bsk[k], Wh[k * D32 + c4], bp);
            }
            part[tid] = bp;
        }
        __syncthreads();
        if (tid < 32) {
            float a = bh[tid];
#pragma unroll
            for (int j = 0; j < 8; ++j) a += part[j * 32 + tid];
            o[1024 + tid] = a;
        }
        __syncthreads();
        for (int i = tid; i < 512; i += 256) {
            int k2 = i >> 5, cc2 = i & 31;
            WCP[lay * 512 + i] = packbf(o[(2 * k2) * 32 + cc2], o[(2 * k2 + 1) * 32 + cc2]);
        }
        return;
    }
    // --- main embed path ---
    float* xs = smem;          // [8][64]
    float* ws = smem + 512;    // [63*32]
    int row0 = blockIdx.x * 8;
    for (int i = tid; i < INCH * D32; i += 256) ws[i] = W[i];
    for (int i = tid; i < 8 * INCH; i += 256) {
        int r = i / INCH, cc = i % INCH;
        int gr = row0 + r;
        xs[r * 64 + cc] = (gr < N) ? x[(size_t)gr * INCH + cc] : 0.f;
    }
    __syncthreads();
    int lr = tid >> 5, c = tid & 31;
    int row = row0 + lr;
    if (row >= N) return;
    float acc = b[c];
#pragma unroll
    for (int k = 0; k < INCH; ++k) acc = fmaf(xs[lr * 64 + k], ws[k * D32 + c], acc);
    float phase = (float)row * c_invf[c >> 1];
    float pe = (c & 1) ? cosf(phase) : sinf(phase);
    H[(size_t)row * D32 + c] = acc + pe;
}

// --- CSR build -------------------------------------------------------------
__global__ void k_scan1(const int* __restrict__ cnt, int* __restrict__ rowptr,
                        int* __restrict__ partials, float* __restrict__ DIS, int N)
{
    __shared__ int s[256];
    int g = blockIdx.x * 256 + threadIdx.x;
    int myc = (g < N) ? cnt[g] : 0;
    if (g < N) DIS[g] = rsqrtf((float)myc + 1.0f);
    s[threadIdx.x] = myc;
    __syncthreads();
    for (int off = 1; off < 256; off <<= 1) {
        int t = (threadIdx.x >= off) ? s[threadIdx.x - off] : 0;
        __syncthreads();
        s[threadIdx.x] += t;
        __syncthreads();
    }
    if (g < N) rowptr[g + 1] = s[threadIdx.x];
    if (threadIdx.x == 255) partials[blockIdx.x] = s[255];
}
// scan3b: per-block prefix of partials computed in-block
__global__ void k_scan3b(int* __restrict__ rowptr, const int* __restrict__ partials,
                         int* __restrict__ cur, int N, int nb)
{
    __shared__ int s[256];
    int t = threadIdx.x;
    s[t] = (t < nb && t < (int)blockIdx.x) ? partials[t] : 0;
    __syncthreads();
    for (int off = 128; off > 0; off >>= 1) {
        if (t < off) s[t] += s[t + off];
        __syncthreads();
    }
    int add = s[0];
    int g = blockIdx.x * 256 + t;
    int oldprev = 0;
    if (g < N && t > 0) oldprev = rowptr[g];
    __syncthreads();
    if (g < N) {
        rowptr[g + 1] += add;
        cur[g] = (t == 0) ? add : oldprev + add;
        if (g == 0) rowptr[0] = 0;
    }
}
__global__ void k_fill(const int* __restrict__ src, const int* __restrict__ dst,
                       int* __restrict__ cur, int* __restrict__ colsrc, int E)
{
    int e = blockIdx.x * 256 + threadIdx.x;
    if (e < E) {
        int p = atomicAdd(&cur[dst[e]], 1);
        colsrc[p] = src[e];
    }
}

// --- Q/K/V/SKIP projections via packed bf16 dot2 ---------------------------
__global__ __launch_bounds__(256) void k_h32_to_kvqs(
    const float* __restrict__ Hm,
    const unsigned* __restrict__ WqP, const float* __restrict__ bq,
    const unsigned* __restrict__ WkP, const float* __restrict__ bk,
    const unsigned* __restrict__ WvP, const float* __restrict__ bv,
    const unsigned* __restrict__ WcP, const float* __restrict__ WCBl,
    unsigned short* __restrict__ Qb, unsigned short* __restrict__ KV,
    float* __restrict__ SKIP, int N)
{
    __shared__ unsigned hp[8][17];
    int row0 = blockIdx.x * 8;
    int c = threadIdx.x;
    if (threadIdx.x < 128) {
        int r = threadIdx.x >> 4, k2 = threadIdx.x & 15;
        int gr = row0 + r;
        float2 hv = (gr < N) ? ((const float2*)Hm)[(size_t)gr * 16 + k2]
                             : make_float2(0.f, 0.f);
        hp[r][k2] = packbf(hv.x, hv.y);
    }
    __syncthreads();
    float aQ[8], aK[8], aV[8], aS[8];
    float bQ = bq[c], bK = bk[c], bV = bv[c];
    float bS = (c < 32) ? WCBl[1024 + c] : 0.f;
#pragma unroll
    for (int r = 0; r < 8; ++r) { aQ[r] = bQ; aK[r] = bK; aV[r] = bV; aS[r] = bS; }
#pragma unroll 4
    for (int k2 = 0; k2 < 16; ++k2) {
        unsigned wq = WqP[k2 * 256 + c];
        unsigned wk = WkP[k2 * 256 + c];
        unsigned wv = WvP[k2 * 256 + c];
        unsigned wc = (c < 32) ? WcP[k2 * 32 + c] : 0u;
#pragma unroll
        for (int r = 0; r < 8; ++r) {
            unsigned h = hp[r][k2];
            DOT2(aQ[r], h, wq);
            DOT2(aK[r], h, wk);
            DOT2(aV[r], h, wv);
            DOT2(aS[r], h, wc);
        }
    }
    int hh = c >> 5, cc = c & 31, ss = cc >> 2, ii = cc & 3;
#pragma unroll
    for (int r = 0; r < 8; ++r) {
        int gr = row0 + r;
        if (gr < N) {
            Qb[(size_t)gr * HCH + c] = f2bf(aQ[r] * CSCALE);
            size_t kb = (size_t)gr * 512 + hh * 64 + ss * 8 + ii;
            KV[kb]     = f2bf(aK[r]);
            KV[kb + 4] = f2bf(aV[r]);
            if (c < 32) SKIP[(size_t)gr * D32 + c] = aS[r];
        }
    }
}

// --- fused attention: wave per dst node, group-of-4 double-buffered --------
#define PROC(A, PIDX)                                                        \
    {                                                                        \
        float t1, t;                                                         \
        asm("v_dot2_f32_bf16 %0, %1, %2, %3"                                 \
            : "=v"(t1) : "v"(A.y), "v"(qy), "v"(zf));                        \
        asm("v_dot2_f32_bf16 %0, %1, %2, %3"                                 \
            : "=v"(t) : "v"(A.x), "v"(qx), "v"(t1));                         \
        t += __shfl_xor(t, 1, 64);                                           \
        t += __shfl_xor(t, 2, 64);                                           \
        t += __shfl_xor(t, 4, 64);                                           \
        float wg = ((PIDX) <= pl) ? __builtin_amdgcn_exp2f(t) : 0.f;         \
        l += wg;                                                             \
        acc0 = fmaf(wg, __uint_as_float(A.z << 16), acc0);                   \
        acc1 = fmaf(wg, __uint_as_float(A.z & 0xffff0000u), acc1);           \
        acc2 = fmaf(wg, __uint_as_float(A.w << 16), acc2);                   \
        acc3 = fmaf(wg, __uint_as_float(A.w & 0xffff0000u), acc3);           \
    }
#define CLD(B, I) colsrc[min((B) + (I), pl)]

__global__ __launch_bounds__(256) void k_attn(
    const uint4* __restrict__ KV4, const uint2* __restrict__ Qb2,
    const float* __restrict__ SKIP, float* __restrict__ H,
    const int* __restrict__ rowptr, const int* __restrict__ colsrc,
    const unsigned* __restrict__ WhP, int N)
{
    __shared__ unsigned osp[4][136];
    int w = threadIdx.x >> 6, lane = threadIdx.x & 63;
    int d = blockIdx.x * 4 + w;
    bool act = d < N;

    unsigned qx = 0u, qy = 0u;
    if (act) {
        uint2 qw = Qb2[(size_t)d * 64 + lane];
        qx = qw.x; qy = qw.y;
    }
    float zf = 0.f;

    float l = 0.f, acc0 = 0.f, acc1 = 0.f, acc2 = 0.f, acc3 = 0.f;
    if (act) {
        int p0 = rowptr[d], p1 = rowptr[d + 1];
        if (p1 > p0) {
            int pl = p1 - 1;
            int s0 = CLD(p0, 0), s1 = CLD(p0, 1), s2 = CLD(p0, 2), s3 = CLD(p0, 3);
            uint4 A0 = KV4[(size_t)s0 * 64 + lane];
            uint4 A1 = KV4[(size_t)s1 * 64 + lane];
            uint4 A2 = KV4[(size_t)s2 * 64 + lane];
            uint4 A3 = KV4[(size_t)s3 * 64 + lane];
#pragma unroll 2
            for (int base = p0; base < p1; base += 4) {
                int nb2 = base + 4;
                int t0 = CLD(nb2, 0), t1c = CLD(nb2, 1), t2c = CLD(nb2, 2), t3c = CLD(nb2, 3);
                uint4 B0 = KV4[(size_t)t0 * 64 + lane];
                uint4 B1 = KV4[(size_t)t1c * 64 + lane];
                uint4 B2 = KV4[(size_t)t2c * 64 + lane];
                uint4 B3 = KV4[(size_t)t3c * 64 + lane];
                PROC(A0, base)
                PROC(A1, base + 1)
                PROC(A2, base + 2)
                PROC(A3, base + 3)
                A0 = B0; A1 = B1; A2 = B2; A3 = B3;
            }
        }
        float inv = (l > 0.f) ? 1.f / l : 0.f;
        int g2 = (lane >> 3) * 16 + (lane & 7) * 2;
        osp[w][g2]     = packbf(acc0 * inv, acc1 * inv);
        osp[w][g2 + 1] = packbf(acc2 * inv, acc3 * inv);
    }
    __syncthreads();

    if (act) {
        int c = lane & 31, half = lane >> 5;
        float a2 = half ? 0.f : SKIP[(size_t)d * D32 + c];
        int kb2 = half * 64;
#pragma unroll 8
        for (int kk = 0; kk < 64; ++kk) {
            unsigned o = osp[w][kb2 + kk];
            unsigned wh = WhP[(kb2 + kk) * 32 + c];
            DOT2(a2, o, wh);
        }
        a2 += __shfl_xor(a2, 32, 64);
        if (lane < 32) H[(size_t)d * D32 + c] = a2;
    }
}

// --- XW3 = DIS * (H @ Wg3), bf16 out ---------------------------------------
__global__ __launch_bounds__(256) void k_xw3(
    const float* __restrict__ X, const float* __restrict__ W,
    const float* __restrict__ DIS, unsigned short* __restrict__ O, int N)
{
    __shared__ float xs[8][33];
    __shared__ float ws[D32 * D32];
    int row0 = blockIdx.x * 8;
    int c = threadIdx.x & 31, lr = threadIdx.x >> 5;
    for (int i = threadIdx.x; i < D32 * D32; i += 256) ws[i] = W[i];
    {
        int gr = row0 + lr;
        xs[lr][c] = (gr < N) ? X[(size_t)gr * D32 + c] : 0.f;
    }
    __syncthreads();
    int row = row0 + lr;
    if (row >= N) return;
    float acc = 0.f;
#pragma unroll
    for (int k = 0; k < D32; ++k) acc = fmaf(xs[lr][k], ws[k * D32 + c], acc);
    O[(size_t)row * D32 + c] = f2bf(DIS[row] * acc);
}

// --- GCN layer 3: gather bf16 XW rows; fused epilogue emits XW4 bf16 -------
__global__ __launch_bounds__(256) void k_gcn_f(
    const unsigned short* __restrict__ XWp, const float* __restrict__ DIS,
    const int* __restrict__ rowptr, const int* __restrict__ colsrc,
    const float* __restrict__ bg, const float* __restrict__ Wg4,
    unsigned short* __restrict__ XWout, int N)
{
    __shared__ float wgs[1024];
    for (int i = threadIdx.x; i < 1024; i += 256) wgs[i] = Wg4[i];
    __syncthreads();
    int g = threadIdx.x >> 5;
    int c = threadIdx.x & 31;
    int d = blockIdx.x * 8 + g;
    bool act = d < N;
    float dd = 0.f, h3 = 0.f;
    if (act) {
        float acc = bfu(XWp[(size_t)d * D32 + c]);
        int p0 = rowptr[d], p1 = rowptr[d + 1];
        if (p1 > p0) {
            int pl = p1 - 1;
            unsigned short uA = XWp[(size_t)CLD(p0, 0) * D32 + c];
            unsigned short uB = XWp[(size_t)CLD(p0, 1) * D32 + c];
            unsigned short uC = XWp[(size_t)CLD(p0, 2) * D32 + c];
            unsigned short uD = XWp[(size_t)CLD(p0, 3) * D32 + c];
#pragma unroll 4
            for (int p = p0; p < p1; ++p) {
                unsigned short uN = XWp[(size_t)CLD(p, 4) * D32 + c];
                acc += bfu(uA);
                uA = uB; uB = uC; uC = uD; uD = uN;
            }
        }
        dd = DIS[d];
        h3 = dd * acc + bg[c];
    }
    float s = 0.f;
#pragma unroll
    for (int k = 0; k < 32; ++k)
        s = fmaf(__shfl(h3, k, 32), wgs[k * D32 + c], s);
    if (act) XWout[(size_t)d * D32 + c] = f2bf(dd * s);
}

// --- GCN layer 4 (final): gather bf16, fp32 out ----------------------------
__global__ __launch_bounds__(256) void k_gcn_last(
    const unsigned short* __restrict__ XWp, const float* __restrict__ DIS,
    const int* __restrict__ rowptr, const int* __restrict__ colsrc,
    const float* __restrict__ bg, float* __restrict__ Out, int N)
{
    int g = threadIdx.x >> 5;
    int c = threadIdx.x & 31;
    int d = blockIdx.x * 8 + g;
    if (d >= N) return;
    float acc = bfu(XWp[(size_t)d * D32 + c]);
    int p0 = rowptr[d], p1 = rowptr[d + 1];
    if (p1 > p0) {
        int pl = p1 - 1;
        unsigned short uA = XWp[(size_t)CLD(p0, 0) * D32 + c];
        unsigned short uB = XWp[(size_t)CLD(p0, 1) * D32 + c];
        unsigned short uC = XWp[(size_t)CLD(p0, 2) * D32 + c];
        unsigned short uD = XWp[(size_t)CLD(p0, 3) * D32 + c];
#pragma unroll 4
        for (int p = p0; p < p1; ++p) {
            unsigned short uN = XWp[(size_t)CLD(p, 4) * D32 + c];
            acc += bfu(uA);
            uA = uB; uB = uC; uC = uD; uD = uN;
        }
    }
    Out[(size_t)d * D32 + c] = DIS[d] * acc + bg[c];
}

// ---------------------------------------------------------------------------
extern "C" void kernel_launch(void* const* d_in, const int* in_sizes, int n_in,
                              void* d_out, int out_size, void* d_ws, size_t ws_size,
                              hipStream_t stream)
{
    const float* x  = (const float*)d_in[0];
    const int*   ei = (const int*)d_in[1];
    const int N = in_sizes[0] / INCH;
    const int E = in_sizes[1] / 2;
    const int* src = ei;
    const int* dst = ei + E;

    const float* W_embed = (const float*)d_in[2];
    const float* b_embed = (const float*)d_in[3];
    const float* Wg3 = (const float*)d_in[24];
    const float* bg3 = (const float*)d_in[25];
    const float* Wg4 = (const float*)d_in[26];
    const float* bg4 = (const float*)d_in[27];

    unsigned short* KV  = (unsigned short*)d_ws;        // N*512 bf16
    unsigned short* Qb  = KV + (size_t)N * 512;         // N*256 bf16
    float* H      = (float*)(Qb + (size_t)N * HCH);     // N*32 f32
    float* SKIP   = H + (size_t)N * D32;                // N*32 f32
    unsigned short* XW1 = (unsigned short*)(SKIP + (size_t)N * D32);  // N*32 bf16
    unsigned short* XW2 = XW1 + (size_t)N * D32;        // N*32 bf16
    int*   rowptr = (int*)(XW2 + (size_t)N * D32);      // N+1
    int*   colsrc = rowptr + (N + 1);                   // E
    int*   cursor = colsrc + E;                         // N
    int*   partials = cursor + N;                       // 256
    float* DIS    = (float*)(partials + 256);           // N
    float* WCB    = DIS + N;                            // 2*1056
    unsigned* WQP = (unsigned*)(WCB + 2 * 1056);        // 2*4096
    unsigned* WKP = WQP + 2 * 4096;                     // 2*4096
    unsigned* WVP = WKP + 2 * 4096;                     // 2*4096
    unsigned* WHP = WVP + 2 * 4096;                     // 2*4096
    unsigned* WCP = WHP + 2 * 4096;                     // 2*512
    float* out    = (float*)d_out;

    const int nb8 = (N + 7) / 8;
    const int nb4 = (N + 3) / 4;
    const int nbN = (N + 255) / 256;
    const int nbE = (E + 255) / 256;

    hipMemsetAsync(cursor, 0, (size_t)N * sizeof(int), stream);

    k_embed<<<nb8 + 10 + nbE, 256, 0, stream>>>(
        x, W_embed, b_embed, H, N, nb8, E, dst, cursor,
        (const float*)d_in[10], (const float*)d_in[11],
        (const float*)d_in[12], (const float*)d_in[13],
        (const float*)d_in[20], (const float*)d_in[21],
        (const float*)d_in[22], (const float*)d_in[23],
        (const float*)d_in[4],  (const float*)d_in[6],  (const float*)d_in[8],
        (const float*)d_in[14], (const float*)d_in[16], (const float*)d_in[18],
        WCB, WQP, WKP, WVP, WHP, WCP);

    k_scan1<<<nbN, 256, 0, stream>>>(cursor, rowptr, partials, DIS, N);
    k_scan3b<<<nbN, 256, 0, stream>>>(rowptr, partials, cursor, N, nbN);
    k_fill<<<nbE, 256, 0, stream>>>(src, dst, cursor, colsrc, E);

    for (int layer = 0; layer < 2; ++layer) {
        int base = 4 + layer * 10;
        const float* bq = (const float*)d_in[base + 1];
        const float* bk = (const float*)d_in[base + 3];
        const float* bv = (const float*)d_in[base + 5];

        k_h32_to_kvqs<<<nb8, 256, 0, stream>>>(
            H,
            WQP + layer * 4096, bq,
            WKP + layer * 4096, bk,
            WVP + layer * 4096, bv,
            WCP + layer * 512, WCB + layer * 1056,
            Qb, KV, SKIP, N);
        k_attn<<<nb4, 256, 0, stream>>>(
            (const uint4*)KV, (const uint2*)Qb, SKIP, H, rowptr, colsrc,
            WHP + layer * 4096, N);
    }

    // XW3 = DIS * (H @ Wg3) in bf16, then GCN gathers
    k_xw3<<<nb8, 256, 0, stream>>>(H, Wg3, DIS, XW1, N);
    k_gcn_f<<<nb8, 256, 0, stream>>>(XW1, DIS, rowptr, colsrc, bg3, Wg4, XW2, N);
    k_gcn_last<<<nb8, 256, 0, stream>>>(XW2, DIS, rowptr, colsrc, bg4, out, N);
}